// Round 6
// baseline (358.769 us; speedup 1.0000x reference)
//
#include <hip/hip_runtime.h>
#include <math.h>

#define B_   4
#define N_   4096
#define D_   1024
#define DFF_ 4096
#define K_   2048

typedef __attribute__((ext_vector_type(8))) short short8;
typedef __attribute__((ext_vector_type(4))) float float4v;

__device__ __forceinline__ unsigned short f2bf(float f) {
    unsigned int u = __float_as_uint(f);
    u = (u + 0x7fffu + ((u >> 16) & 1u)) >> 16;   // RNE
    return (unsigned short)u;
}

__device__ __forceinline__ void gld16(const void* g, void* l) {
    __builtin_amdgcn_global_load_lds((const __attribute__((address_space(1))) void*)g,
                                     (__attribute__((address_space(3))) void*)l, 16, 0, 0);
}

// ---------------- merged: scores (blocks 0..4095, bit-identical math) + weight transposes ----------------
__global__ __launch_bounds__(256) void scores_transpose_kernel(const float* __restrict__ x,
                                                               const float* __restrict__ gate_w,
                                                               float* __restrict__ scores,
                                                               int* __restrict__ slot,
                                                               const float* __restrict__ w1,
                                                               const float* __restrict__ w2,
                                                               unsigned short* __restrict__ w1t,
                                                               unsigned short* __restrict__ w2t) {
    __shared__ float tile[32][33];
    int bid = blockIdx.x;
    if (bid < 4096) {
        int wave = (bid * 256 + threadIdx.x) >> 6;
        int lane = threadIdx.x & 63;
        if (lane == 1) slot[wave] = -1;
        const float4* xr = (const float4*)(x + (size_t)wave * D_);
        const float4* g  = (const float4*)gate_w;
        float acc = 0.f;
        #pragma unroll
        for (int j = 0; j < D_ / 4 / 64; ++j) {
            float4 a = xr[lane + j * 64];
            float4 b = g[lane + j * 64];
            acc += a.x * b.x + a.y * b.y + a.z * b.z + a.w * b.w;
        }
        #pragma unroll
        for (int off = 32; off > 0; off >>= 1) acc += __shfl_down(acc, off, 64);
        if (lane == 0) scores[wave] = acc;
        return;
    }
    int tb = bid - 4096;
    const float* src; unsigned short* dst; int R, C, bx, by;
    if (tb < 4096) { src = w1; dst = w1t; R = D_;   C = DFF_; bx = tb & 127;          by = tb >> 7; }
    else           { src = w2; dst = w2t; R = DFF_; C = D_;   bx = (tb - 4096) & 31;  by = (tb - 4096) >> 5; }
    int tx = threadIdx.x & 31, ty = threadIdx.x >> 5;   // 32 x 8
    int c = bx * 32 + tx, r0 = by * 32;
    #pragma unroll
    for (int j = ty; j < 32; j += 8) tile[j][tx] = src[(size_t)(r0 + j) * C + c];
    __syncthreads();
    int dc = by * 32 + tx, dr0 = bx * 32;
    #pragma unroll
    for (int j = ty; j < 32; j += 8) dst[(size_t)(dr0 + j) * R + dc] = f2bf(tile[tx][j]);
}

// ---------------- top-k radix select, wave-level scans; writes topk + global slot map ----------------
__global__ __launch_bounds__(1024) void select_topk_kernel(const float* __restrict__ scores,
                                                           int* __restrict__ topk,
                                                           int* __restrict__ slot) {
    __shared__ unsigned key[N_];
    __shared__ unsigned hist[256];
    __shared__ int sh_bin, sh_rem, sh_ngt;
    __shared__ int wsum[16], woff[16];
    int b = blockIdx.x, tid = threadIdx.x;
    int lane = tid & 63, wid = tid >> 6;

    for (int i = tid; i < N_; i += 1024) {
        unsigned u = __float_as_uint(scores[b * N_ + i]);
        key[i] = (u & 0x80000000u) ? ~u : (u | 0x80000000u);   // monotonic map
    }
    if (tid == 0) sh_ngt = 0;
    __syncthreads();

    unsigned prefix = 0, pmask = 0;
    int rem = K_;
    for (int shift = 24; shift >= 0; shift -= 8) {
        if (tid < 256) hist[tid] = 0;
        __syncthreads();
        for (int i = tid; i < N_; i += 1024) {
            unsigned k = key[i];
            if ((k & pmask) == prefix) atomicAdd(&hist[(k >> shift) & 255u], 1u);
        }
        __syncthreads();
        if (tid < 64) {   // wave 0: suffix scan of 256 bins, 4 bins/lane
            unsigned v0 = hist[4 * lane], v1 = hist[4 * lane + 1];
            unsigned v2 = hist[4 * lane + 2], v3 = hist[4 * lane + 3];
            unsigned s3 = v3, s2 = v2 + s3, s1 = v1 + s2, s0 = v0 + s1;
            unsigned t = s0;
            #pragma unroll
            for (int off = 1; off < 64; off <<= 1) {
                unsigned u = __shfl_down(t, off, 64);
                if (lane + off < 64) t += u;
            }
            unsigned above = t - s0;
            unsigned S0 = s0 + above, S1 = s1 + above, S2 = s2 + above, S3 = s3 + above;
            unsigned R = (unsigned)rem;
            if (S0 >= R && S1 < R) { sh_bin = 4 * lane;     sh_rem = rem - (int)S1; }
            if (S1 >= R && S2 < R) { sh_bin = 4 * lane + 1; sh_rem = rem - (int)S2; }
            if (S2 >= R && S3 < R) { sh_bin = 4 * lane + 2; sh_rem = rem - (int)S3; }
            if (S3 >= R && above < R) { sh_bin = 4 * lane + 3; sh_rem = rem - (int)above; }
        }
        __syncthreads();
        prefix |= ((unsigned)sh_bin) << shift;
        pmask  |= 0xffu << shift;
        rem = sh_rem;
    }
    unsigned T = prefix;
    int c_gt = K_ - rem;

    for (int i = tid; i < N_; i += 1024) {
        bool p = key[i] > T;
        unsigned long long m = __ballot(p);
        int cnt = __popcll(m);
        int basepos = 0;
        if (lane == 0 && cnt) basepos = atomicAdd(&sh_ngt, cnt);
        basepos = __shfl(basepos, 0, 64);
        if (p) {
            int pos = basepos + __popcll(m & ((1ULL << lane) - 1ULL));
            topk[b * K_ + pos] = i;
            slot[b * N_ + i] = b * K_ + pos;
        }
    }
    int base = tid * 4, c = 0;
    #pragma unroll
    for (int j = 0; j < 4; ++j) c += (key[base + j] == T);
    int sc = c;
    #pragma unroll
    for (int off = 1; off < 64; off <<= 1) {
        int u = __shfl_up(sc, off, 64);
        if (lane >= off) sc += u;
    }
    if (lane == 63) wsum[wid] = sc;
    __syncthreads();
    if (tid == 0) {
        int run = 0;
        #pragma unroll
        for (int j = 0; j < 16; ++j) { woff[j] = run; run += wsum[j]; }
    }
    __syncthreads();
    int r = woff[wid] + sc - c;
    #pragma unroll
    for (int j = 0; j < 4; ++j) {
        if (key[base + j] == T) {
            if (r < rem) {
                topk[b * K_ + c_gt + r] = base + j;
                slot[b * N_ + base + j] = b * K_ + c_gt + r;
            }
            ++r;
        }
    }
}

// ---------------- fused: selected rows -> bf16 xsel[slot]; unselected -> out copy ----------------
__global__ __launch_bounds__(256) void gather_copy_kernel(const float* __restrict__ x,
                                                          const int* __restrict__ slot,
                                                          unsigned short* __restrict__ xsel,
                                                          float* __restrict__ out) {
    int row = blockIdx.x;
    int t = threadIdx.x;
    int s = slot[row];
    float4 v = ((const float4*)(x + (size_t)row * D_))[t];
    if (s >= 0) {
        ushort4 o;
        o.x = f2bf(v.x); o.y = f2bf(v.y); o.z = f2bf(v.z); o.w = f2bf(v.w);
        ((ushort4*)(xsel + (size_t)s * D_))[t] = o;
    } else {
        ((float4*)(out + (size_t)row * D_))[t] = v;
    }
}

// ---------------- MFMA GEMM 1: h1 = gelu(x_sel @ w1 + b1); coalesced epilogue via LDS ----------------
__global__ __launch_bounds__(256) void ffn1_mfma_kernel(const unsigned short* __restrict__ A,
                                                        const unsigned short* __restrict__ Bt,
                                                        const float* __restrict__ b1,
                                                        unsigned short* __restrict__ h1) {
    constexpr int K = D_;                 // 1024
    __shared__ __align__(16) char smem[16896];   // staging 16 KB | epilogue Cs 64x132 bf16 = 16.5 KB
    unsigned short* As = (unsigned short*)smem;
    unsigned short* Bs = As + 4096;
    unsigned short* Cs = (unsigned short*)smem;
    int t = threadIdx.x;
    int w = t >> 6, lane = t & 63;
    int quad = lane >> 4, lr = lane & 15;
    int wm = w >> 1, wn = w & 1;
    int row0 = blockIdx.x * 128, col0 = blockIdx.y * 128;

    const char* ga0 = (const char*)(A + (size_t)(row0 + (t >> 2)) * K) + (t & 3) * 16;
    const char* ga1 = ga0 + (size_t)64 * K * 2;
    const char* gb0 = (const char*)(Bt + (size_t)(col0 + (t >> 2)) * K) + (t & 3) * 16;
    const char* gb1 = gb0 + (size_t)64 * K * 2;
    unsigned short* la0 = As + t * 8;   unsigned short* la1 = As + 2048 + t * 8;
    unsigned short* lb0 = Bs + t * 8;   unsigned short* lb1 = Bs + 2048 + t * 8;

    float4v acc[4][4] = {};
    for (int k0 = 0; k0 < K; k0 += 32) {
        gld16(ga0, la0); gld16(ga1, la1);
        gld16(gb0, lb0); gld16(gb1, lb1);
        ga0 += 64; ga1 += 64; gb0 += 64; gb1 += 64;
        __syncthreads();
        short8 af[4], bfv[4];
        #pragma unroll
        for (int mi = 0; mi < 4; ++mi)
            af[mi] = *(const short8*)(As + (size_t)(wm * 64 + mi * 16 + lr) * 32 + quad * 8);
        #pragma unroll
        for (int ni = 0; ni < 4; ++ni)
            bfv[ni] = *(const short8*)(Bs + (size_t)(wn * 64 + ni * 16 + lr) * 32 + quad * 8);
        #pragma unroll
        for (int mi = 0; mi < 4; ++mi)
            #pragma unroll
            for (int ni = 0; ni < 4; ++ni)
                acc[mi][ni] = __builtin_amdgcn_mfma_f32_16x16x32_bf16(af[mi], bfv[ni], acc[mi][ni], 0, 0, 0);
        __syncthreads();
    }

    #pragma unroll
    for (int half = 0; half < 2; ++half) {
        __syncthreads();
        #pragma unroll
        for (int mi2 = 0; mi2 < 2; ++mi2) {
            int mi = half * 2 + mi2;
            #pragma unroll
            for (int ni = 0; ni < 4; ++ni) {
                int col = wn * 64 + ni * 16 + lr;
                float bias = b1[col0 + col];
                #pragma unroll
                for (int r = 0; r < 4; ++r) {
                    int lrow = wm * 32 + mi2 * 16 + quad * 4 + r;
                    float u = acc[mi][ni][r] + bias;
                    float tt = 1.5957691216057308f * u * (1.0f + 0.044715f * u * u);
                    float g = u / (1.0f + __expf(-tt));
                    Cs[lrow * 132 + col] = f2bf(g);
                }
            }
        }
        __syncthreads();
        #pragma unroll
        for (int kch = 0; kch < 4; ++kch) {
            int ch = t + kch * 256;               // 0..1023
            int lrow = ch >> 4;                   // 0..63
            int off = (ch & 15) * 8;
            int grow = row0 + ((lrow >> 5) << 6) + half * 32 + (lrow & 31);
            *(short8*)(h1 + (size_t)grow * DFF_ + col0 + off) = *(const short8*)(Cs + lrow * 132 + off);
        }
    }
}

// ---------------- MFMA GEMM 2: out[sel] = x_sel + h1 @ w2 + b2; coalesced epilogue via LDS ----------------
__global__ __launch_bounds__(256) void ffn2_mfma_kernel(const unsigned short* __restrict__ A,
                                                        const unsigned short* __restrict__ Bt,
                                                        const float* __restrict__ b2,
                                                        const float* __restrict__ x,
                                                        const int* __restrict__ topk,
                                                        float* __restrict__ out) {
    constexpr int K = DFF_;               // 4096
    __shared__ __align__(16) char smem[16896];   // staging 16 KB | epilogue Cs 32x132 fp32 = 16.5 KB
    unsigned short* As = (unsigned short*)smem;
    unsigned short* Bs = As + 4096;
    float* Cs = (float*)smem;
    int t = threadIdx.x;
    int w = t >> 6, lane = t & 63;
    int quad = lane >> 4, lr = lane & 15;
    int wm = w >> 1, wn = w & 1;
    int row0 = blockIdx.x * 128, col0 = blockIdx.y * 128;

    const char* ga0 = (const char*)(A + (size_t)(row0 + (t >> 2)) * K) + (t & 3) * 16;
    const char* ga1 = ga0 + (size_t)64 * K * 2;
    const char* gb0 = (const char*)(Bt + (size_t)(col0 + (t >> 2)) * K) + (t & 3) * 16;
    const char* gb1 = gb0 + (size_t)64 * K * 2;
    unsigned short* la0 = As + t * 8;   unsigned short* la1 = As + 2048 + t * 8;
    unsigned short* lb0 = Bs + t * 8;   unsigned short* lb1 = Bs + 2048 + t * 8;

    float4v acc[4][4] = {};
    for (int k0 = 0; k0 < K; k0 += 32) {
        gld16(ga0, la0); gld16(ga1, la1);
        gld16(gb0, lb0); gld16(gb1, lb1);
        ga0 += 64; ga1 += 64; gb0 += 64; gb1 += 64;
        __syncthreads();
        short8 af[4], bfv[4];
        #pragma unroll
        for (int mi = 0; mi < 4; ++mi)
            af[mi] = *(const short8*)(As + (size_t)(wm * 64 + mi * 16 + lr) * 32 + quad * 8);
        #pragma unroll
        for (int ni = 0; ni < 4; ++ni)
            bfv[ni] = *(const short8*)(Bs + (size_t)(wn * 64 + ni * 16 + lr) * 32 + quad * 8);
        #pragma unroll
        for (int mi = 0; mi < 4; ++mi)
            #pragma unroll
            for (int ni = 0; ni < 4; ++ni)
                acc[mi][ni] = __builtin_amdgcn_mfma_f32_16x16x32_bf16(af[mi], bfv[ni], acc[mi][ni], 0, 0, 0);
        __syncthreads();
    }

    // epilogue: 4 quarters of 32 rows; repack in LDS then fully-coalesced row segments
    #pragma unroll
    for (int q = 0; q < 4; ++q) {
        __syncthreads();
        if (wm == (q >> 1)) {
            #pragma unroll
            for (int mi2 = 0; mi2 < 2; ++mi2) {
                int mi = (q & 1) * 2 + mi2;
                #pragma unroll
                for (int ni = 0; ni < 4; ++ni) {
                    int col = wn * 64 + ni * 16 + lr;
                    #pragma unroll
                    for (int r = 0; r < 4; ++r)
                        Cs[(mi2 * 16 + quad * 4 + r) * 132 + col] = acc[mi][ni][r];
                }
            }
        }
        __syncthreads();
        #pragma unroll
        for (int kch = 0; kch < 4; ++kch) {
            int ch = t + kch * 256;               // 0..1023
            int lrow = ch >> 5;                   // 0..31
            int c4 = (ch & 31) * 4;               // float offset within 128 cols
            int grow = row0 + q * 32 + lrow;
            int gb = grow >> 11;
            int tok = topk[grow];
            size_t base = ((size_t)(gb * N_ + tok)) * D_ + col0 + c4;
            float4 xv = *(const float4*)(x + base);
            float4 bv = *(const float4*)(b2 + col0 + c4);
            const float* cp = Cs + lrow * 132 + c4;
            float4 o;
            o.x = xv.x + cp[0] + bv.x;
            o.y = xv.y + cp[1] + bv.y;
            o.z = xv.z + cp[2] + bv.z;
            o.w = xv.w + cp[3] + bv.w;
            *(float4*)(out + base) = o;
        }
    }
}

extern "C" void kernel_launch(void* const* d_in, const int* in_sizes, int n_in,
                              void* d_out, int out_size, void* d_ws, size_t ws_size,
                              hipStream_t stream) {
    const float* x      = (const float*)d_in[0];
    const float* gate_w = (const float*)d_in[1];
    const float* w1     = (const float*)d_in[2];
    const float* b1     = (const float*)d_in[3];
    const float* w2     = (const float*)d_in[4];
    const float* b2     = (const float*)d_in[5];
    float* out = (float*)d_out;

    char* ws = (char*)d_ws;
    float*          scores = (float*)ws;                                        // 64 KiB
    int*            topk   = (int*)(ws + (64 << 10));                           // 32 KiB
    int*            slot   = (int*)(ws + (96 << 10));                           // 64 KiB
    unsigned short* xsel   = (unsigned short*)(ws + (160 << 10));               // 16 MiB
    unsigned short* w1t    = (unsigned short*)(ws + (160 << 10) + (16 << 20));  // 8 MiB  [4096][1024]
    unsigned short* w2t    = (unsigned short*)(ws + (160 << 10) + (24 << 20));  // 8 MiB  [1024][4096]
    unsigned short* h1     = (unsigned short*)(ws + (160 << 10) + (32 << 20));  // 64 MiB [8192][4096]

    scores_transpose_kernel<<<12288, 256, 0, stream>>>(x, gate_w, scores, slot, w1, w2, w1t, w2t);
    select_topk_kernel<<<B_, 1024, 0, stream>>>(scores, topk, slot);
    gather_copy_kernel<<<B_ * N_, 256, 0, stream>>>(x, slot, xsel, out);

    ffn1_mfma_kernel<<<dim3(64, 32), 256, 0, stream>>>(xsel, w1t, b1, h1);
    ffn2_mfma_kernel<<<dim3(64, 8), 256, 0, stream>>>(h1, w2t, b2, x, topk, out);
}